// Round 7
// baseline (211.991 us; speedup 1.0000x reference)
//
#include <hip/hip_runtime.h>
#include <hip/hip_bf16.h>
#include <hip/hip_fp16.h>

using half8  = __attribute__((ext_vector_type(8))) _Float16;
using float4v = __attribute__((ext_vector_type(4))) float;
using f32x16 = __attribute__((ext_vector_type(16))) float;
typedef unsigned int uint;

#define A_DIM 4
#define M_DIM 2048
#define E_DIM 1024
#define H_DIM 16
#define C_DIM 64
#define PLANE (M_DIM * C_DIM)              // 131072 elements per (a,h)
#define PROJ_ELEMS (A_DIM * H_DIM * PLANE) // 8388608
#define LOG2E 1.44269504088896f

#define GLOAD_LDS16(g, l) __builtin_amdgcn_global_load_lds( \
    (const __attribute__((address_space(1))) void*)(g), \
    (__attribute__((address_space(3))) void*)(l), 16, 0, 0)

#if __has_builtin(__builtin_amdgcn_exp2f)
#define EXP2F(x) __builtin_amdgcn_exp2f(x)
#else
#define EXP2F(x) exp2f(x)
#endif

// f32 pair -> packed fp16 (RTZ) as uint bits
static __device__ __forceinline__ uint pk16(float a, float b) {
    auto r = __builtin_amdgcn_cvt_pkrtz(a, b);   // __fp16 x2
    return __builtin_bit_cast(uint, r);
}

// read 8 logical-contiguous f32 from a swizzled LDS tile row (128B row
// stride, 16B blocks XOR'd by (row&7)<<4), convert to half8.
static __device__ __forceinline__ half8 ldsfrag_cvt32(const float* base, int row, int gb) {
    const char* b = (const char*)base;
    int off = row * 128 + (gb ^ ((row & 7) << 4));
    float4v x0 = *reinterpret_cast<const float4v*>(b + off);
    float4v x1 = *reinterpret_cast<const float4v*>(b + (off ^ 16));
    union { uint u[4]; half8 v; } r;
    r.u[0] = pk16(x0[0], x0[1]);
    r.u[1] = pk16(x0[2], x0[3]);
    r.u[2] = pk16(x1[0], x1[1]);
    r.u[3] = pk16(x1[2], x1[3]);
    return r.v;
}

// ---------------------------------------------------------------------------
// Merged projection GEMM: grid.y = z in {0,1,2} selects (X,W,b,out).
// out = X @ W^T + b, fp16 out. BK=32, DOUBLE-BUFFERED global_load_lds staging
// (pre-swizzled source, rule 21), f32->f16 at fragment read (cvt_pkrtz).
// XCD-grouped remap: each XCD owns an 8-R0 band with all 8 C0s -> X band
// fetched once per XCD-L2.
// z<2: out[a][h][m][c] ; z==2: out[a][h][c][t] (transposed V)
// ---------------------------------------------------------------------------
__global__ __launch_bounds__(256, 2)
void proj_kernel(const float* __restrict__ q, const float* __restrict__ k,
                 const float* __restrict__ v,
                 const float* __restrict__ Wq, const float* __restrict__ Wk,
                 const float* __restrict__ Wv,
                 const float* __restrict__ bq, const float* __restrict__ bk,
                 const float* __restrict__ bv,
                 _Float16* __restrict__ qp, _Float16* __restrict__ kp,
                 _Float16* __restrict__ vt)
{
    __shared__ float ldsA[2][128 * 32];   // 2 x 16 KB
    __shared__ float ldsB[2][128 * 32];   // 2 x 16 KB

    const int z = blockIdx.y;
    const float* X    = (z == 0) ? q  : (z == 1) ? k  : v;
    const float* W    = (z == 0) ? Wq : (z == 1) ? Wk : Wv;
    const float* bias = (z == 0) ? bq : (z == 1) ? bk : bv;
    _Float16* out     = (z == 0) ? qp : (z == 1) ? kp : vt;
    const bool TR = (z == 2);

    // XCD-grouped remap: bid%8 = xcd (hw round-robin); each xcd gets
    // R0-band [xcd*8, xcd*8+8) x all 8 C0s.
    const int bid = blockIdx.x;
    const int xcd = bid & 7;
    const int idx = bid >> 3;                 // 0..63
    const int R0 = (xcd * 8 + (idx >> 3)) * 128;
    const int C0 = (idx & 7) * 128;

    const int tid  = threadIdx.x;
    const int lane = tid & 63;
    const int wave = tid >> 6;
    const int wr = wave >> 1, wc = wave & 1;
    const int g = lane >> 4, r16 = lane & 15;

    auto stage = [&](int buf, int k0) {
#pragma unroll
        for (int i = 0; i < 4; i++) {
            int seg  = i * 256 + tid;          // 0..1023 (16B units)
            int row  = seg >> 3;               // 0..127
            int swzo = ((seg & 7) * 16) ^ ((row & 7) << 4);
            const char* asrc = (const char*)&X[(size_t)(R0 + row) * E_DIM + k0] + swzo;
            const char* bsrc = (const char*)&W[(size_t)(C0 + row) * E_DIM + k0] + swzo;
            GLOAD_LDS16(asrc, &ldsA[buf][seg * 4]);
            GLOAD_LDS16(bsrc, &ldsB[buf][seg * 4]);
        }
    };

    float4v acc[4][4];
#pragma unroll
    for (int i = 0; i < 4; i++)
#pragma unroll
        for (int j = 0; j < 4; j++) acc[i][j] = {0.f, 0.f, 0.f, 0.f};

    stage(0, 0);

    for (int it = 0; it < E_DIM / 32; ++it) {
        __syncthreads();                       // publishes buf[it&1] (vmcnt drain)
        if (it + 1 < E_DIM / 32) stage((it + 1) & 1, (it + 1) * 32);
        const float* A = ldsA[it & 1];
        const float* B = ldsB[it & 1];

        half8 af[4], bf[4];
#pragma unroll
        for (int mi = 0; mi < 4; mi++)
            af[mi] = ldsfrag_cvt32(A, wr * 64 + mi * 16 + r16, g * 32);
#pragma unroll
        for (int ni = 0; ni < 4; ni++)
            bf[ni] = ldsfrag_cvt32(B, wc * 64 + ni * 16 + r16, g * 32);
#pragma unroll
        for (int mi = 0; mi < 4; mi++)
#pragma unroll
            for (int ni = 0; ni < 4; ni++)
                acc[mi][ni] = __builtin_amdgcn_mfma_f32_16x16x32_f16(af[mi], bf[ni], acc[mi][ni], 0, 0, 0);
    }

    // epilogue: D layout col = lane&15, row = g*4 + reg
#pragma unroll
    for (int mi = 0; mi < 4; mi++) {
#pragma unroll
        for (int ni = 0; ni < 4; ni++) {
            const int jb = C0 + wc * 64 + ni * 16 + r16;
            const int h  = jb >> 6;
            const int cc = jb & 63;
            const float bv = bias[jb];
            if (!TR) {
#pragma unroll
                for (int reg = 0; reg < 4; reg++) {
                    int b = R0 + wr * 64 + mi * 16 + g * 4 + reg;
                    float val = acc[mi][ni][reg] + bv;
                    size_t o = (size_t)((b >> 11) * H_DIM + h) * PLANE + (size_t)(b & (M_DIM - 1)) * C_DIM + cc;
                    out[o] = (_Float16)val;
                }
            } else {
                int b0 = R0 + wr * 64 + mi * 16 + g * 4;
                uint u0 = pk16(acc[mi][ni][0] + bv, acc[mi][ni][1] + bv);
                uint u1 = pk16(acc[mi][ni][2] + bv, acc[mi][ni][3] + bv);
                size_t o = (size_t)((b0 >> 11) * H_DIM + h) * PLANE + (size_t)cc * M_DIM + (b0 & (M_DIM - 1));
                *reinterpret_cast<uint*>(&out[o]) = u0;
                *reinterpret_cast<uint*>(&out[o] + 2) = u1;
            }
        }
    }
}

// ---------------------------------------------------------------------------
// Flash attention (FROZEN from R5/R6): swapped-QK^T 32x32, shfl_xor pack,
// max3 tree, exp2+fma, uniform defer-max, setprio on MFMA. ~105 us measured.
// ---------------------------------------------------------------------------
__global__ __launch_bounds__(256, 4)
void flash_kernel(const _Float16* __restrict__ qp, const _Float16* __restrict__ kp,
                  const _Float16* __restrict__ vt, float* __restrict__ out)
{
    __shared__ _Float16 smem[2][2][4096];   // [dbuf][K|V][64 rows x 64 cols]

    const int tid  = threadIdx.x;
    const int lane = tid & 63;
    const int wave = tid >> 6;
    const int l31  = lane & 31;
    const int hi   = lane >> 5;

    const int bid = blockIdx.x;
    const int wg  = ((bid & 7) << 7) | (bid >> 3);
    const int plane_i = wg >> 4;
    const int qt      = wg & 15;
    const size_t plane = (size_t)plane_i * PLANE;
    const int q0 = qt * 128 + wave * 32;

    const int srow  = tid >> 3;
    const int lincb = (tid & 7) * 16;
    const int scb   = lincb ^ ((srow & 7) << 4);

    half8 qf[4];
#pragma unroll
    for (int ch = 0; ch < 4; ch++)
        qf[ch] = *reinterpret_cast<const half8*>(&qp[plane + (size_t)(q0 + l31) * C_DIM + ch * 16 + hi * 8]);

    f32x16 o0, o1;
#pragma unroll
    for (int i = 0; i < 16; i++) { o0[i] = 0.f; o1[i] = 0.f; }
    float m = -INFINITY, l = 0.f;

    auto stage = [&](int buf, int t0) {
#pragma unroll
        for (int i = 0; i < 2; i++) {
            int row = srow + 32 * i;
            const char* ksrc = (const char*)&kp[plane + (size_t)(t0 + row) * C_DIM] + scb;
            const char* vsrc = (const char*)&vt[plane + (size_t)row * M_DIM + t0] + scb;
            GLOAD_LDS16(ksrc, &smem[buf][0][tid * 8 + 2048 * i]);
            GLOAD_LDS16(vsrc, &smem[buf][1][tid * 8 + 2048 * i]);
        }
    };

    stage(0, 0);

    for (int it = 0; it < M_DIM / 64; ++it) {
        __syncthreads();
        if (it + 1 < M_DIM / 64) stage((it + 1) & 1, (it + 1) * 64);
        const int cur = it & 1;
        const char* kbase = (const char*)smem[cur][0];
        const char* vbase = (const char*)smem[cur][1];

#pragma unroll
        for (int st = 0; st < 2; ++st) {
            const int krow = st * 32 + l31;
            const int kswz = (krow & 7) << 4;
            f32x16 s;
#pragma unroll
            for (int i = 0; i < 16; i++) s[i] = 0.f;
            __builtin_amdgcn_s_setprio(1);
#pragma unroll
            for (int ch = 0; ch < 4; ch++) {
                int cb = (ch * 32 + hi * 16) ^ kswz;
                half8 kf = *reinterpret_cast<const half8*>(kbase + krow * 128 + cb);
                s = __builtin_amdgcn_mfma_f32_32x32x16_f16(kf, qf[ch], s, 0, 0, 0);
            }
            __builtin_amdgcn_s_setprio(0);

            float a0 = fmaxf(fmaxf(s[0],  s[1]),  s[2]);
            float a1 = fmaxf(fmaxf(s[3],  s[4]),  s[5]);
            float a2 = fmaxf(fmaxf(s[6],  s[7]),  s[8]);
            float a3 = fmaxf(fmaxf(s[9],  s[10]), s[11]);
            float a4 = fmaxf(fmaxf(s[12], s[13]), s[14]);
            float pm = fmaxf(fmaxf(fmaxf(a0, a1), a2),
                             fmaxf(fmaxf(a3, a4), s[15]));
            pm = fmaxf(pm, __shfl_xor(pm, 32));
            if (!__all(pm <= m + 8.f)) {
                float mnew = fmaxf(m, pm);
                float sc = EXP2F((m - mnew) * LOG2E);
                m = mnew; l *= sc;
                o0 *= sc; o1 *= sc;
            }
            const float mK = m * LOG2E;
            float p[16];
#pragma unroll
            for (int r = 0; r < 16; r++) p[r] = EXP2F(fmaf(s[r], LOG2E, -mK));
            float t0a = (p[0] + p[1]) + (p[2] + p[3]);
            float t1a = (p[4] + p[5]) + (p[6] + p[7]);
            float t2a = (p[8] + p[9]) + (p[10] + p[11]);
            float t3a = (p[12] + p[13]) + (p[14] + p[15]);
            l += (t0a + t1a) + (t2a + t3a);

            half8 pf[2];
#pragma unroll
            for (int c0 = 0; c0 < 2; c0++) {
                uint ua0 = pk16(p[8 * c0 + 0], p[8 * c0 + 1]);
                uint ua1 = pk16(p[8 * c0 + 2], p[8 * c0 + 3]);
                uint ub0 = pk16(p[8 * c0 + 4], p[8 * c0 + 5]);
                uint ub1 = pk16(p[8 * c0 + 6], p[8 * c0 + 7]);
                uint v0 = hi ? ua0 : ub0;
                uint v1 = hi ? ua1 : ub1;
                uint y0 = (uint)__shfl_xor((int)v0, 32);
                uint y1 = (uint)__shfl_xor((int)v1, 32);
                union { uint u[4]; half8 v; } pu;
                pu.u[0] = hi ? y0 : ua0;
                pu.u[1] = hi ? y1 : ua1;
                pu.u[2] = hi ? ub0 : y0;
                pu.u[3] = hi ? ub1 : y1;
                pf[c0] = pu.v;
            }

            __builtin_amdgcn_s_setprio(1);
#pragma unroll
            for (int db = 0; db < 2; db++) {
                const int vrow = db * 32 + l31;
                const int vswz = (vrow & 7) << 4;
#pragma unroll
                for (int c0 = 0; c0 < 2; c0++) {
                    int cb = (st * 64 + c0 * 32 + hi * 16) ^ vswz;
                    half8 vf = *reinterpret_cast<const half8*>(vbase + vrow * 128 + cb);
                    if (db == 0) o0 = __builtin_amdgcn_mfma_f32_32x32x16_f16(vf, pf[c0], o0, 0, 0, 0);
                    else         o1 = __builtin_amdgcn_mfma_f32_32x32x16_f16(vf, pf[c0], o1, 0, 0, 0);
                }
            }
            __builtin_amdgcn_s_setprio(0);
        }
    }

    const int aa = plane_i >> 4;
    const int hh = plane_i & 15;
    const float lt = l + __shfl_xor(l, 32);
    const float inv = 1.f / lt;
    float* obase = out + ((size_t)(aa * M_DIM + q0 + l31)) * E_DIM + hh * C_DIM;
#pragma unroll
    for (int db = 0; db < 2; db++) {
#pragma unroll
        for (int g4 = 0; g4 < 4; g4++) {
            float4v w;
#pragma unroll
            for (int j = 0; j < 4; j++) w[j] = (db ? o1[4 * g4 + j] : o0[4 * g4 + j]) * inv;
            int d0 = db * 32 + 8 * g4 + 4 * hi;
            *reinterpret_cast<float4v*>(obase + d0) = w;
        }
    }
}

extern "C" void kernel_launch(void* const* d_in, const int* in_sizes, int n_in,
                              void* d_out, int out_size, void* d_ws, size_t ws_size,
                              hipStream_t stream)
{
    const float* q  = (const float*)d_in[0];
    const float* k  = (const float*)d_in[1];
    const float* v  = (const float*)d_in[2];
    const float* Wq = (const float*)d_in[3];
    const float* bq = (const float*)d_in[4];
    const float* Wk = (const float*)d_in[5];
    const float* bk = (const float*)d_in[6];
    const float* Wv = (const float*)d_in[7];
    const float* bv = (const float*)d_in[8];
    float* out = (float*)d_out;

    _Float16* qp = (_Float16*)d_ws;
    _Float16* kp = qp + PROJ_ELEMS;
    _Float16* vt = kp + PROJ_ELEMS;

    hipLaunchKernelGGL(proj_kernel, dim3(512, 3), dim3(256), 0, stream,
                       q, k, v, Wq, Wk, Wv, bq, bk, bv, qp, kp, vt);
    hipLaunchKernelGGL(flash_kernel, dim3(A_DIM * H_DIM * (M_DIM / 128)), dim3(256), 0, stream, qp, kp, vt, out);
}